// Round 2
// baseline (910.908 us; speedup 1.0000x reference)
//
#include <hip/hip_runtime.h>
#include <cmath>

// Sinkhorn divergence (geomloss-style, debiased) between softmax rows.
//  1) gram_kernel: double-buffered LDS, dwordx4 global loads, fp32 exp,
//     per-block fp32 partial records of Gxy/Gxx/Gyy (16x16 each) + row sums.
//  2) reduce_kernel: 3x8 blocks, fp64 private sums, ~19K low-contention atomics.
//  3) sinkhorn_kernel: 6 blocks x 64 threads, register-resident 60-step loop,
//     fp32 expm1/log1p polynomials (LSE_j(logw+d_j) = log1p(mean_j expm1(d_j))).
//  4) finalize_kernel: combine 3 pair divergences -> d_out.

#define TPB 256
#define CHUNK 128
#define NCH 8
#define COLS_PER_BLOCK (CHUNK * NCH)   // 1024
#define NSTEP 60

struct EpsList { float e[NSTEP]; };

struct GramArgs {
  const float* x0; const float* y0;
  const float* x1; const float* y1;
  const float* x2; const float* y2;
  int M0, M1, M2;
  int bs1, bs2;      // first block id of pair 1 / pair 2
  float* partial;    // [numBlocks][800] fp32, or null in atomic mode
  double* finalG;    // [3][800] doubles
  int atomicMode;
};

// LDS word index of rows [4*rg .. 4*rg+3] of column c (XOR-swizzled col-major).
// 16B-aligned (both terms are multiples of 4 words); bijective in rg per column.
__device__ __forceinline__ int ldsWord(int c, int rg) {
  return c * 16 + ((((c >> 2) ^ rg) & 3) << 2);
}

__global__ __launch_bounds__(TPB, 4) void gram_kernel(GramArgs A) {
  __shared__ __align__(16) float sE[2][2][CHUNK * 16];   // [buf][mat][...]
  __shared__ float zstage[32];

  const int bid = blockIdx.x;
  int p, lb;
  if (bid >= A.bs2)      { p = 2; lb = bid - A.bs2; }
  else if (bid >= A.bs1) { p = 1; lb = bid - A.bs1; }
  else                   { p = 0; lb = bid; }
  const float* X = (p == 0) ? A.x0 : (p == 1) ? A.x1 : A.x2;
  const float* Y = (p == 0) ? A.y0 : (p == 1) ? A.y1 : A.y2;
  const int M    = (p == 0) ? A.M0 : (p == 1) ? A.M1 : A.M2;

  const int t = threadIdx.x;
  // loader mapping: thread owns 4 consecutive cols x 4 rows of ONE matrix
  const int g   = t & 31;        // column group (cols 4g..4g+3)
  const int h   = t >> 5;        // 0..7
  const int hw  = h & 3;         // row group (rows 4hw..4hw+3)
  const int mat = h >> 2;        // 0: x, 1: y
  const float* P = mat ? Y : X;
  const size_t colbase = (size_t)lb * COLS_PER_BLOCK;
  const float* lp = P + (size_t)(4 * hw) * M + colbase + 4 * g;

  // FMA mapping: 16 slices x 16 (4x4) tiles
  const int slice = t & 15;
  const int tile  = t >> 4;
  const int ti    = tile >> 2;
  const int tk    = tile & 3;

  float axy[4][4] = {};
  float axx[4][4] = {};
  float ayy[4][4] = {};
  float z[4] = {};

  float4 L[4];
  #pragma unroll
  for (int q = 0; q < 4; ++q)
    L[q] = *reinterpret_cast<const float4*>(lp + (size_t)q * M);

  auto stage = [&](int nb) {
    float e[4][4];
    #pragma unroll
    for (int q = 0; q < 4; ++q) {
      e[q][0] = expf(L[q].x); e[q][1] = expf(L[q].y);
      e[q][2] = expf(L[q].z); e[q][3] = expf(L[q].w);
      z[q] += (e[q][0] + e[q][1]) + (e[q][2] + e[q][3]);
    }
    #pragma unroll
    for (int j = 0; j < 4; ++j) {
      *reinterpret_cast<float4*>(&sE[nb][mat][ldsWord(4 * g + j, hw)]) =
          make_float4(e[0][j], e[1][j], e[2][j], e[3][j]);
    }
  };

  stage(0);
  __syncthreads();

  #pragma unroll 1
  for (int ch = 0; ch < NCH; ++ch) {
    const int cur = ch & 1;
    if (ch + 1 < NCH) {
      const float* np = lp + (size_t)(ch + 1) * CHUNK;
      #pragma unroll
      for (int q = 0; q < 4; ++q)
        L[q] = *reinterpret_cast<const float4*>(np + (size_t)q * M);
    }
    const float* bx = sE[cur][0];
    const float* by = sE[cur][1];
    #pragma unroll
    for (int s = 0; s < CHUNK / 16; ++s) {
      const int c = slice + 16 * s;
      const float4 xi = *reinterpret_cast<const float4*>(&bx[ldsWord(c, ti)]);
      const float4 xk = *reinterpret_cast<const float4*>(&bx[ldsWord(c, tk)]);
      const float4 yi = *reinterpret_cast<const float4*>(&by[ldsWord(c, ti)]);
      const float4 yk = *reinterpret_cast<const float4*>(&by[ldsWord(c, tk)]);
      const float xiA[4] = {xi.x, xi.y, xi.z, xi.w};
      const float xkA[4] = {xk.x, xk.y, xk.z, xk.w};
      const float yiA[4] = {yi.x, yi.y, yi.z, yi.w};
      const float ykA[4] = {yk.x, yk.y, yk.z, yk.w};
      #pragma unroll
      for (int r = 0; r < 4; ++r) {
        #pragma unroll
        for (int u = 0; u < 4; ++u) {
          axy[r][u] = fmaf(xiA[r], ykA[u], axy[r][u]);
          axx[r][u] = fmaf(xiA[r], xkA[u], axx[r][u]);
          ayy[r][u] = fmaf(yiA[r], ykA[u], ayy[r][u]);
        }
      }
    }
    if (ch + 1 < NCH) {
      stage(cur ^ 1);
      __syncthreads();
    }
  }

  // ---- Gram tile reduction across slice lanes (bits 0..3) ----
  float* rec = A.atomicMode ? nullptr : (A.partial + (size_t)bid * 800);
  double* fin = A.finalG + p * 800;
  #pragma unroll
  for (int r = 0; r < 4; ++r) {
    #pragma unroll
    for (int u = 0; u < 4; ++u) {
      float v0 = axy[r][u], v1 = axx[r][u], v2 = ayy[r][u];
      #pragma unroll
      for (int d = 1; d <= 8; d <<= 1) {
        v0 += __shfl_xor(v0, d);
        v1 += __shfl_xor(v1, d);
        v2 += __shfl_xor(v2, d);
      }
      if (slice == 0) {
        const int idx = (4 * ti + r) * 16 + (4 * tk + u);
        if (A.atomicMode) {
          atomicAdd(&fin[idx],       (double)v0);
          atomicAdd(&fin[256 + idx], (double)v1);
          atomicAdd(&fin[512 + idx], (double)v2);
        } else {
          rec[idx] = v0; rec[256 + idx] = v1; rec[512 + idx] = v2;
        }
      }
    }
  }
  // ---- Z reduction: butterfly over the 32 column-group lanes ----
  #pragma unroll
  for (int d = 1; d <= 16; d <<= 1) {
    #pragma unroll
    for (int q = 0; q < 4; ++q) z[q] += __shfl_xor(z[q], d);
  }
  if (g == 0) {
    #pragma unroll
    for (int q = 0; q < 4; ++q) zstage[mat * 16 + 4 * hw + q] = z[q];
  }
  __syncthreads();
  if (t < 32) {
    const float s = zstage[t];
    if (A.atomicMode) atomicAdd(&fin[768 + t], (double)s);
    else              rec[768 + t] = s;
  }
}

// 3 pairs x 8 splits; fp64 private sums, low-contention atomics.
__global__ __launch_bounds__(256) void reduce_kernel(const float* __restrict__ partial,
                                                     double* __restrict__ finalG,
                                                     int nb0, int nb1, int nb2) {
  const int p   = blockIdx.x >> 3;
  const int k   = blockIdx.x & 7;
  const int cnt = (p == 0) ? nb0 : (p == 1) ? nb1 : nb2;
  const int st  = (p == 0) ? 0   : (p == 1) ? nb0 : nb0 + nb1;
  for (int v = threadIdx.x; v < 800; v += 256) {
    double s = 0.0;
    for (int r = k; r < cnt; r += 8)
      s += (double)partial[(size_t)(st + r) * 800 + v];
    atomicAdd(&finalG[p * 800 + v], s);
  }
}

__device__ __forceinline__ float expm1_poly(float d) {
  float p = 1.0f / 120.0f;
  p = fmaf(p, d, 1.0f / 24.0f);
  p = fmaf(p, d, 1.0f / 6.0f);
  p = fmaf(p, d, 0.5f);
  return fmaf(d * d, p, d);
}
__device__ __forceinline__ float log1p_poly(float w) {
  float p = -1.0f / 6.0f;
  p = fmaf(p, w, 1.0f / 5.0f);
  p = fmaf(p, w, -1.0f / 4.0f);
  p = fmaf(p, w, 1.0f / 3.0f);
  p = fmaf(p, w, -0.5f);
  return fmaf(w * w, p, w);
}

// blocks: 2p -> (f,g) chains of pair p ; 2p+1 -> (a,b) self chains
__global__ __launch_bounds__(64) void sinkhorn_kernel(const double* __restrict__ finalG,
                                                      double* __restrict__ result,
                                                      EpsList E) {
  const int p    = blockIdx.x >> 1;
  const int half = blockIdx.x & 1;
  const int lane = threadIdx.x;
  const int pot  = lane >> 5;
  const int i    = (lane >> 1) & 15;
  const int jh   = lane & 1;
  const double* G = finalG + p * 800;

  float Crow[8];
  #pragma unroll
  for (int jj = 0; jj < 8; ++jj) {
    const int j = jh * 8 + jj;
    double Cv;
    if (half == 0) {
      const int r = (pot == 0) ? i : j;
      const int c = (pot == 0) ? j : i;
      const double zr = G[768 + r], zc = G[784 + c];
      const double sr = G[256 + 17 * r] / (zr * zr);
      const double sc = G[512 + 17 * c] / (zc * zc);
      Cv = 0.5 * (sr + sc) - G[16 * r + c] / (zr * zc);
    } else if (pot == 0) {
      const double zi_ = G[768 + i], zj_ = G[768 + j];
      const double si_ = G[256 + 17 * i] / (zi_ * zi_);
      const double sj_ = G[256 + 17 * j] / (zj_ * zj_);
      Cv = 0.5 * (si_ + sj_) - G[256 + 16 * i + j] / (zi_ * zj_);
    } else {
      const double zi_ = G[784 + i], zj_ = G[784 + j];
      const double si_ = G[512 + 17 * i] / (zi_ * zi_);
      const double sj_ = G[512 + 17 * j] / (zj_ * zj_);
      Cv = 0.5 * (si_ + sj_) - G[512 + 16 * i + j] / (zi_ * zj_);
    }
    Crow[jj] = (float)Cv;
  }

  const int srcBase = (half == 0) ? ((pot == 0) ? 32 : 0)
                                  : ((pot == 0) ? 0 : 32);
  float h = 0.0f;

  #pragma unroll 1
  for (int n = 0; n < NSTEP; ++n) {
    const float eps  = E.e[n];
    const float inve = 1.0f / eps;
    float q = 0.0f;
    #pragma unroll
    for (int jj = 0; jj < 8; ++jj) {
      const float hj = __shfl(h, srcBase + 2 * (jh * 8 + jj));
      q += expm1_poly((hj - Crow[jj]) * inve);
    }
    q += __shfl_xor(q, 1);
    const float val = -eps * log1p_poly(q * (1.0f / 16.0f));
    h = 0.5f * (h + val);
  }
  {
    const float eps  = 0.0025f;
    const float inve = 1.0f / eps;
    float q = 0.0f;
    #pragma unroll
    for (int jj = 0; jj < 8; ++jj) {
      const float hj = __shfl(h, srcBase + 2 * (jh * 8 + jj));
      q += expm1_poly((hj - Crow[jj]) * inve);
    }
    q += __shfl_xor(q, 1);
    h = -eps * log1p_poly(q * (1.0f / 16.0f));
  }
  float s = h;
  #pragma unroll
  for (int d = 1; d <= 32; d <<= 1) s += __shfl_xor(s, d);
  if (lane == 0) result[blockIdx.x] = (double)(s * (1.0f / 32.0f));
}

__global__ void finalize_kernel(const double* __restrict__ result, float* __restrict__ out) {
  const double s = (result[0] - result[1]) + (result[2] - result[3]) + (result[4] - result[5]);
  out[0] = (float)(s / 3.0);
}

extern "C" void kernel_launch(void* const* d_in, const int* in_sizes, int n_in,
                              void* d_out, int out_size, void* d_ws, size_t ws_size,
                              hipStream_t stream) {
  int idx[6] = {0, 1, 2, 3, 4, 5};
  for (int a = 1; a < 6; ++a) {
    const int key = idx[a];
    int b = a - 1;
    while (b >= 0 && in_sizes[idx[b]] < in_sizes[key]) { idx[b + 1] = idx[b]; --b; }
    idx[b + 1] = key;
  }

  const float* xs[3]; const float* ys[3]; int Ms[3]; int nb[3];
  for (int p = 0; p < 3; ++p) {
    xs[p] = (const float*)d_in[idx[2 * p]];
    ys[p] = (const float*)d_in[idx[2 * p + 1]];
    Ms[p] = in_sizes[idx[2 * p]] / 16;
    nb[p] = Ms[p] / COLS_PER_BLOCK;
  }
  const int totalBlocks = nb[0] + nb[1] + nb[2];

  const size_t partialBytes = (size_t)totalBlocks * 800 * sizeof(float);
  const size_t finalBytes   = (size_t)(2400 + 8) * sizeof(double);
  const bool partialMode    = (ws_size >= partialBytes + finalBytes);

  char* wsb      = (char*)d_ws;
  float* partial = partialMode ? (float*)wsb : nullptr;
  double* finalG = (double*)(wsb + (partialMode ? partialBytes : 0));
  double* result = finalG + 2400;

  hipMemsetAsync(finalG, 0, finalBytes, stream);

  GramArgs A;
  A.x0 = xs[0]; A.y0 = ys[0];
  A.x1 = xs[1]; A.y1 = ys[1];
  A.x2 = xs[2]; A.y2 = ys[2];
  A.M0 = Ms[0]; A.M1 = Ms[1]; A.M2 = Ms[2];
  A.bs1 = nb[0]; A.bs2 = nb[0] + nb[1];
  A.partial = partial; A.finalG = finalG;
  A.atomicMode = partialMode ? 0 : 1;

  gram_kernel<<<dim3(totalBlocks), dim3(TPB), 0, stream>>>(A);
  if (partialMode)
    reduce_kernel<<<dim3(24), dim3(256), 0, stream>>>(partial, finalG, nb[0], nb[1], nb[2]);

  EpsList E;
  const double base = 0.95 * 0.95;
  for (int n = 0; n < NSTEP; ++n) {
    double v = pow(base, (double)n);
    if (v < 0.0025) v = 0.0025;
    E.e[n] = (float)v;
  }
  sinkhorn_kernel<<<dim3(6), dim3(64), 0, stream>>>(finalG, result, E);
  finalize_kernel<<<dim3(1), dim3(1), 0, stream>>>(result, (float*)d_out);
}

// Round 3
// 385.040 us; speedup vs baseline: 2.3657x; 2.3657x over previous
//
#include <hip/hip_runtime.h>
#include <cmath>

// Sinkhorn divergence (geomloss-style, debiased) between softmax rows.
//  1) gram_kernel: double-buffered LDS, dwordx4 global loads, __expf,
//     per-block fp32 partial records of Gxy/Gxx/Gyy (16x16 each) + row sums.
//     NOTE: no min-waves clause in __launch_bounds__ — (256,4) clamped the
//     allocator to 64 VGPRs and spilled the 48 accumulators to scratch
//     (1.39 GB of writes, 9x regression). Plain (256) allocates ~freely.
//  2) reduce_kernel: 3x8 blocks, fp64 private sums, low-contention atomics.
//  3) sinkhorn_kernel: 6 blocks x 64 threads, register-resident 60-step loop,
//     fp32 expm1/log1p polynomials (LSE_j(logw+d_j) = log1p(mean_j expm1(d_j))).
//  4) finalize_kernel: combine 3 pair divergences -> d_out.

#define TPB 256
#define CHUNK 128
#define NCH 8
#define COLS_PER_BLOCK (CHUNK * NCH)   // 1024
#define NSTEP 60

struct EpsList { float e[NSTEP]; };

struct GramArgs {
  const float* x0; const float* y0;
  const float* x1; const float* y1;
  const float* x2; const float* y2;
  int M0, M1, M2;
  int bs1, bs2;      // first block id of pair 1 / pair 2
  float* partial;    // [numBlocks][800] fp32, or null in atomic mode
  double* finalG;    // [3][800] doubles
  int atomicMode;
};

// LDS word index of rows [4*rg .. 4*rg+3] of column c (XOR-swizzled col-major).
__device__ __forceinline__ int ldsWord(int c, int rg) {
  return c * 16 + ((((c >> 2) ^ rg) & 3) << 2);
}

__global__ __launch_bounds__(TPB) void gram_kernel(GramArgs A) {
  __shared__ __align__(16) float sE[2][2][CHUNK * 16];   // [buf][mat][...]
  __shared__ float zstage[32];

  const int bid = blockIdx.x;
  int p, lb;
  if (bid >= A.bs2)      { p = 2; lb = bid - A.bs2; }
  else if (bid >= A.bs1) { p = 1; lb = bid - A.bs1; }
  else                   { p = 0; lb = bid; }
  const float* X = (p == 0) ? A.x0 : (p == 1) ? A.x1 : A.x2;
  const float* Y = (p == 0) ? A.y0 : (p == 1) ? A.y1 : A.y2;
  const int M    = (p == 0) ? A.M0 : (p == 1) ? A.M1 : A.M2;

  const int t = threadIdx.x;
  // loader mapping: thread owns 4 consecutive cols x 4 rows of ONE matrix
  const int g   = t & 31;        // column group (cols 4g..4g+3)
  const int h   = t >> 5;        // 0..7
  const int hw  = h & 3;         // row group (rows 4hw..4hw+3)
  const int mat = h >> 2;        // 0: x, 1: y
  const float* P = mat ? Y : X;
  const size_t colbase = (size_t)lb * COLS_PER_BLOCK;
  const float* lp = P + (size_t)(4 * hw) * M + colbase + 4 * g;

  // FMA mapping: 16 slices x 16 (4x4) tiles
  const int slice = t & 15;
  const int tile  = t >> 4;
  const int ti    = tile >> 2;
  const int tk    = tile & 3;

  float axy[4][4] = {};
  float axx[4][4] = {};
  float ayy[4][4] = {};
  float z[4] = {};

  float4 L[4];
  #pragma unroll
  for (int q = 0; q < 4; ++q)
    L[q] = *reinterpret_cast<const float4*>(lp + (size_t)q * M);

  auto stage = [&](int nb) {
    float e[4][4];
    #pragma unroll
    for (int q = 0; q < 4; ++q) {
      e[q][0] = __expf(L[q].x); e[q][1] = __expf(L[q].y);
      e[q][2] = __expf(L[q].z); e[q][3] = __expf(L[q].w);
      z[q] += (e[q][0] + e[q][1]) + (e[q][2] + e[q][3]);
    }
    #pragma unroll
    for (int j = 0; j < 4; ++j) {
      *reinterpret_cast<float4*>(&sE[nb][mat][ldsWord(4 * g + j, hw)]) =
          make_float4(e[0][j], e[1][j], e[2][j], e[3][j]);
    }
  };

  stage(0);
  __syncthreads();

  #pragma unroll 1
  for (int ch = 0; ch < NCH; ++ch) {
    const int cur = ch & 1;
    if (ch + 1 < NCH) {
      const float* np = lp + (size_t)(ch + 1) * CHUNK;
      #pragma unroll
      for (int q = 0; q < 4; ++q)
        L[q] = *reinterpret_cast<const float4*>(np + (size_t)q * M);
    }
    const float* bx = sE[cur][0];
    const float* by = sE[cur][1];
    #pragma unroll
    for (int s = 0; s < CHUNK / 16; ++s) {
      const int c = slice + 16 * s;
      const float4 xi = *reinterpret_cast<const float4*>(&bx[ldsWord(c, ti)]);
      const float4 xk = *reinterpret_cast<const float4*>(&bx[ldsWord(c, tk)]);
      const float4 yi = *reinterpret_cast<const float4*>(&by[ldsWord(c, ti)]);
      const float4 yk = *reinterpret_cast<const float4*>(&by[ldsWord(c, tk)]);
      const float xiA[4] = {xi.x, xi.y, xi.z, xi.w};
      const float xkA[4] = {xk.x, xk.y, xk.z, xk.w};
      const float yiA[4] = {yi.x, yi.y, yi.z, yi.w};
      const float ykA[4] = {yk.x, yk.y, yk.z, yk.w};
      #pragma unroll
      for (int r = 0; r < 4; ++r) {
        #pragma unroll
        for (int u = 0; u < 4; ++u) {
          axy[r][u] = fmaf(xiA[r], ykA[u], axy[r][u]);
          axx[r][u] = fmaf(xiA[r], xkA[u], axx[r][u]);
          ayy[r][u] = fmaf(yiA[r], ykA[u], ayy[r][u]);
        }
      }
    }
    if (ch + 1 < NCH) {
      stage(cur ^ 1);
      __syncthreads();
    }
  }

  // ---- Gram tile reduction across slice lanes (bits 0..3) ----
  float* rec = A.atomicMode ? nullptr : (A.partial + (size_t)bid * 800);
  double* fin = A.finalG + p * 800;
  #pragma unroll
  for (int r = 0; r < 4; ++r) {
    #pragma unroll
    for (int u = 0; u < 4; ++u) {
      float v0 = axy[r][u], v1 = axx[r][u], v2 = ayy[r][u];
      #pragma unroll
      for (int d = 1; d <= 8; d <<= 1) {
        v0 += __shfl_xor(v0, d);
        v1 += __shfl_xor(v1, d);
        v2 += __shfl_xor(v2, d);
      }
      if (slice == 0) {
        const int idx = (4 * ti + r) * 16 + (4 * tk + u);
        if (A.atomicMode) {
          atomicAdd(&fin[idx],       (double)v0);
          atomicAdd(&fin[256 + idx], (double)v1);
          atomicAdd(&fin[512 + idx], (double)v2);
        } else {
          rec[idx] = v0; rec[256 + idx] = v1; rec[512 + idx] = v2;
        }
      }
    }
  }
  // ---- Z reduction: butterfly over the 32 column-group lanes ----
  #pragma unroll
  for (int d = 1; d <= 16; d <<= 1) {
    #pragma unroll
    for (int q = 0; q < 4; ++q) z[q] += __shfl_xor(z[q], d);
  }
  if (g == 0) {
    #pragma unroll
    for (int q = 0; q < 4; ++q) zstage[mat * 16 + 4 * hw + q] = z[q];
  }
  __syncthreads();
  if (t < 32) {
    const float s = zstage[t];
    if (A.atomicMode) atomicAdd(&fin[768 + t], (double)s);
    else              rec[768 + t] = s;
  }
}

// 3 pairs x 8 splits; fp64 private sums, low-contention atomics.
__global__ __launch_bounds__(256) void reduce_kernel(const float* __restrict__ partial,
                                                     double* __restrict__ finalG,
                                                     int nb0, int nb1, int nb2) {
  const int p   = blockIdx.x >> 3;
  const int k   = blockIdx.x & 7;
  const int cnt = (p == 0) ? nb0 : (p == 1) ? nb1 : nb2;
  const int st  = (p == 0) ? 0   : (p == 1) ? nb0 : nb0 + nb1;
  for (int v = threadIdx.x; v < 800; v += 256) {
    double s = 0.0;
    for (int r = k; r < cnt; r += 8)
      s += (double)partial[(size_t)(st + r) * 800 + v];
    atomicAdd(&finalG[p * 800 + v], s);
  }
}

__device__ __forceinline__ float expm1_poly(float d) {
  float p = 1.0f / 120.0f;
  p = fmaf(p, d, 1.0f / 24.0f);
  p = fmaf(p, d, 1.0f / 6.0f);
  p = fmaf(p, d, 0.5f);
  return fmaf(d * d, p, d);
}
__device__ __forceinline__ float log1p_poly(float w) {
  float p = -1.0f / 6.0f;
  p = fmaf(p, w, 1.0f / 5.0f);
  p = fmaf(p, w, -1.0f / 4.0f);
  p = fmaf(p, w, 1.0f / 3.0f);
  p = fmaf(p, w, -0.5f);
  return fmaf(w * w, p, w);
}

// blocks: 2p -> (f,g) chains of pair p ; 2p+1 -> (a,b) self chains
__global__ __launch_bounds__(64) void sinkhorn_kernel(const double* __restrict__ finalG,
                                                      double* __restrict__ result,
                                                      EpsList E) {
  const int p    = blockIdx.x >> 1;
  const int half = blockIdx.x & 1;
  const int lane = threadIdx.x;
  const int pot  = lane >> 5;
  const int i    = (lane >> 1) & 15;
  const int jh   = lane & 1;
  const double* G = finalG + p * 800;

  float Crow[8];
  #pragma unroll
  for (int jj = 0; jj < 8; ++jj) {
    const int j = jh * 8 + jj;
    double Cv;
    if (half == 0) {
      const int r = (pot == 0) ? i : j;
      const int c = (pot == 0) ? j : i;
      const double zr = G[768 + r], zc = G[784 + c];
      const double sr = G[256 + 17 * r] / (zr * zr);
      const double sc = G[512 + 17 * c] / (zc * zc);
      Cv = 0.5 * (sr + sc) - G[16 * r + c] / (zr * zc);
    } else if (pot == 0) {
      const double zi_ = G[768 + i], zj_ = G[768 + j];
      const double si_ = G[256 + 17 * i] / (zi_ * zi_);
      const double sj_ = G[256 + 17 * j] / (zj_ * zj_);
      Cv = 0.5 * (si_ + sj_) - G[256 + 16 * i + j] / (zi_ * zj_);
    } else {
      const double zi_ = G[784 + i], zj_ = G[784 + j];
      const double si_ = G[512 + 17 * i] / (zi_ * zi_);
      const double sj_ = G[512 + 17 * j] / (zj_ * zj_);
      Cv = 0.5 * (si_ + sj_) - G[512 + 16 * i + j] / (zi_ * zj_);
    }
    Crow[jj] = (float)Cv;
  }

  const int srcBase = (half == 0) ? ((pot == 0) ? 32 : 0)
                                  : ((pot == 0) ? 0 : 32);
  float h = 0.0f;

  #pragma unroll 1
  for (int n = 0; n < NSTEP; ++n) {
    const float eps  = E.e[n];
    const float inve = 1.0f / eps;
    float q = 0.0f;
    #pragma unroll
    for (int jj = 0; jj < 8; ++jj) {
      const float hj = __shfl(h, srcBase + 2 * (jh * 8 + jj));
      q += expm1_poly((hj - Crow[jj]) * inve);
    }
    q += __shfl_xor(q, 1);
    const float val = -eps * log1p_poly(q * (1.0f / 16.0f));
    h = 0.5f * (h + val);
  }
  {
    const float eps  = 0.0025f;
    const float inve = 1.0f / eps;
    float q = 0.0f;
    #pragma unroll
    for (int jj = 0; jj < 8; ++jj) {
      const float hj = __shfl(h, srcBase + 2 * (jh * 8 + jj));
      q += expm1_poly((hj - Crow[jj]) * inve);
    }
    q += __shfl_xor(q, 1);
    h = -eps * log1p_poly(q * (1.0f / 16.0f));
  }
  float s = h;
  #pragma unroll
  for (int d = 1; d <= 32; d <<= 1) s += __shfl_xor(s, d);
  if (lane == 0) result[blockIdx.x] = (double)(s * (1.0f / 32.0f));
}

__global__ void finalize_kernel(const double* __restrict__ result, float* __restrict__ out) {
  const double s = (result[0] - result[1]) + (result[2] - result[3]) + (result[4] - result[5]);
  out[0] = (float)(s / 3.0);
}

extern "C" void kernel_launch(void* const* d_in, const int* in_sizes, int n_in,
                              void* d_out, int out_size, void* d_ws, size_t ws_size,
                              hipStream_t stream) {
  int idx[6] = {0, 1, 2, 3, 4, 5};
  for (int a = 1; a < 6; ++a) {
    const int key = idx[a];
    int b = a - 1;
    while (b >= 0 && in_sizes[idx[b]] < in_sizes[key]) { idx[b + 1] = idx[b]; --b; }
    idx[b + 1] = key;
  }

  const float* xs[3]; const float* ys[3]; int Ms[3]; int nb[3];
  for (int p = 0; p < 3; ++p) {
    xs[p] = (const float*)d_in[idx[2 * p]];
    ys[p] = (const float*)d_in[idx[2 * p + 1]];
    Ms[p] = in_sizes[idx[2 * p]] / 16;
    nb[p] = Ms[p] / COLS_PER_BLOCK;
  }
  const int totalBlocks = nb[0] + nb[1] + nb[2];

  const size_t partialBytes = (size_t)totalBlocks * 800 * sizeof(float);
  const size_t finalBytes   = (size_t)(2400 + 8) * sizeof(double);
  const bool partialMode    = (ws_size >= partialBytes + finalBytes);

  char* wsb      = (char*)d_ws;
  float* partial = partialMode ? (float*)wsb : nullptr;
  double* finalG = (double*)(wsb + (partialMode ? partialBytes : 0));
  double* result = finalG + 2400;

  hipMemsetAsync(finalG, 0, finalBytes, stream);

  GramArgs A;
  A.x0 = xs[0]; A.y0 = ys[0];
  A.x1 = xs[1]; A.y1 = ys[1];
  A.x2 = xs[2]; A.y2 = ys[2];
  A.M0 = Ms[0]; A.M1 = Ms[1]; A.M2 = Ms[2];
  A.bs1 = nb[0]; A.bs2 = nb[0] + nb[1];
  A.partial = partial; A.finalG = finalG;
  A.atomicMode = partialMode ? 0 : 1;

  gram_kernel<<<dim3(totalBlocks), dim3(TPB), 0, stream>>>(A);
  if (partialMode)
    reduce_kernel<<<dim3(24), dim3(256), 0, stream>>>(partial, finalG, nb[0], nb[1], nb[2]);

  EpsList E;
  const double base = 0.95 * 0.95;
  for (int n = 0; n < NSTEP; ++n) {
    double v = pow(base, (double)n);
    if (v < 0.0025) v = 0.0025;
    E.e[n] = (float)v;
  }
  sinkhorn_kernel<<<dim3(6), dim3(64), 0, stream>>>(finalG, result, E);
  finalize_kernel<<<dim3(1), dim3(1), 0, stream>>>(result, (float*)d_out);
}

// Round 4
// 282.489 us; speedup vs baseline: 3.2246x; 1.3630x over previous
//
#include <hip/hip_runtime.h>
#include <cmath>

// Sinkhorn divergence (geomloss-style, debiased) between softmax rows.
//  1) gram_kernel: double-buffered LDS, dwordx4 global loads, __expf,
//     per-block fp32 partials of Gxy/Gxx/Gyy (16x16) + row sums, written
//     TRANSPOSED: partial[800*start_p + v*cnt_p + lb] so the reducer reads
//     contiguous runs. (Epilogue stores were scattered dwords anyway.)
//     NOTE: no min-waves clause in __launch_bounds__ — (256,4) clamped the
//     allocator to 64 VGPRs and spilled the 48 accumulators to scratch
//     (1.39 GB of writes, 9x regression). Plain (256) allocates ~freely.
//  2) reduce_kernel: one block per (pair, value) = 2400 blocks; coalesced
//     contiguous read of cnt floats, fp64 block reduction, plain store.
//     (R3's 24-block strided version was 124 us: 0.5% occupancy, serial
//     uncoalesced gathers. Layout transpose + 100x blocks -> ~3 us.)
//  3) sinkhorn_kernel: 6 blocks x 64 threads, register-resident 60-step loop,
//     fp32 expm1/log1p polynomials (LSE_j(logw+d_j) = log1p(mean_j expm1(d_j))).
//  4) finalize_kernel: combine 3 pair divergences -> d_out.

#define TPB 256
#define CHUNK 128
#define NCH 8
#define COLS_PER_BLOCK (CHUNK * NCH)   // 1024
#define NSTEP 60

struct EpsList { float e[NSTEP]; };

struct GramArgs {
  const float* x0; const float* y0;
  const float* x1; const float* y1;
  const float* x2; const float* y2;
  int M0, M1, M2;
  int bs1, bs2, bsTot;   // prefix starts of pair 1 / pair 2, total blocks
  float* partial;        // transposed per-pair: [800][cnt_p] fp32
  double* finalG;        // [3][800] doubles
  int atomicMode;
};

// LDS word index of rows [4*rg .. 4*rg+3] of column c (XOR-swizzled col-major).
__device__ __forceinline__ int ldsWord(int c, int rg) {
  return c * 16 + ((((c >> 2) ^ rg) & 3) << 2);
}

__global__ __launch_bounds__(TPB) void gram_kernel(GramArgs A) {
  __shared__ __align__(16) float sE[2][2][CHUNK * 16];   // [buf][mat][...]
  __shared__ float zstage[32];

  const int bid = blockIdx.x;
  int p, lb, start, cnt;
  if (bid >= A.bs2)      { p = 2; lb = bid - A.bs2; start = A.bs2; cnt = A.bsTot - A.bs2; }
  else if (bid >= A.bs1) { p = 1; lb = bid - A.bs1; start = A.bs1; cnt = A.bs2 - A.bs1; }
  else                   { p = 0; lb = bid;         start = 0;     cnt = A.bs1; }
  const float* X = (p == 0) ? A.x0 : (p == 1) ? A.x1 : A.x2;
  const float* Y = (p == 0) ? A.y0 : (p == 1) ? A.y1 : A.y2;
  const int M    = (p == 0) ? A.M0 : (p == 1) ? A.M1 : A.M2;

  const int t = threadIdx.x;
  // loader mapping: thread owns 4 consecutive cols x 4 rows of ONE matrix
  const int g   = t & 31;        // column group (cols 4g..4g+3)
  const int h   = t >> 5;        // 0..7
  const int hw  = h & 3;         // row group (rows 4hw..4hw+3)
  const int mat = h >> 2;        // 0: x, 1: y
  const float* P = mat ? Y : X;
  const size_t colbase = (size_t)lb * COLS_PER_BLOCK;
  const float* lp = P + (size_t)(4 * hw) * M + colbase + 4 * g;

  // FMA mapping: 16 slices x 16 (4x4) tiles
  const int slice = t & 15;
  const int tile  = t >> 4;
  const int ti    = tile >> 2;
  const int tk    = tile & 3;

  float axy[4][4] = {};
  float axx[4][4] = {};
  float ayy[4][4] = {};
  float z[4] = {};

  float4 L[4];
  #pragma unroll
  for (int q = 0; q < 4; ++q)
    L[q] = *reinterpret_cast<const float4*>(lp + (size_t)q * M);

  auto stage = [&](int nb) {
    float e[4][4];
    #pragma unroll
    for (int q = 0; q < 4; ++q) {
      e[q][0] = __expf(L[q].x); e[q][1] = __expf(L[q].y);
      e[q][2] = __expf(L[q].z); e[q][3] = __expf(L[q].w);
      z[q] += (e[q][0] + e[q][1]) + (e[q][2] + e[q][3]);
    }
    #pragma unroll
    for (int j = 0; j < 4; ++j) {
      *reinterpret_cast<float4*>(&sE[nb][mat][ldsWord(4 * g + j, hw)]) =
          make_float4(e[0][j], e[1][j], e[2][j], e[3][j]);
    }
  };

  stage(0);
  __syncthreads();

  #pragma unroll 1
  for (int ch = 0; ch < NCH; ++ch) {
    const int cur = ch & 1;
    if (ch + 1 < NCH) {
      const float* np = lp + (size_t)(ch + 1) * CHUNK;
      #pragma unroll
      for (int q = 0; q < 4; ++q)
        L[q] = *reinterpret_cast<const float4*>(np + (size_t)q * M);
    }
    const float* bx = sE[cur][0];
    const float* by = sE[cur][1];
    #pragma unroll
    for (int s = 0; s < CHUNK / 16; ++s) {
      const int c = slice + 16 * s;
      const float4 xi = *reinterpret_cast<const float4*>(&bx[ldsWord(c, ti)]);
      const float4 xk = *reinterpret_cast<const float4*>(&bx[ldsWord(c, tk)]);
      const float4 yi = *reinterpret_cast<const float4*>(&by[ldsWord(c, ti)]);
      const float4 yk = *reinterpret_cast<const float4*>(&by[ldsWord(c, tk)]);
      const float xiA[4] = {xi.x, xi.y, xi.z, xi.w};
      const float xkA[4] = {xk.x, xk.y, xk.z, xk.w};
      const float yiA[4] = {yi.x, yi.y, yi.z, yi.w};
      const float ykA[4] = {yk.x, yk.y, yk.z, yk.w};
      #pragma unroll
      for (int r = 0; r < 4; ++r) {
        #pragma unroll
        for (int u = 0; u < 4; ++u) {
          axy[r][u] = fmaf(xiA[r], ykA[u], axy[r][u]);
          axx[r][u] = fmaf(xiA[r], xkA[u], axx[r][u]);
          ayy[r][u] = fmaf(yiA[r], ykA[u], ayy[r][u]);
        }
      }
    }
    if (ch + 1 < NCH) {
      stage(cur ^ 1);
      __syncthreads();
    }
  }

  // ---- Gram tile reduction across slice lanes (bits 0..3) ----
  // transposed partial: value v of this block -> partial[800*start + v*cnt + lb]
  float* rec = A.atomicMode ? nullptr : (A.partial + (size_t)800 * start + lb);
  double* fin = A.finalG + p * 800;
  #pragma unroll
  for (int r = 0; r < 4; ++r) {
    #pragma unroll
    for (int u = 0; u < 4; ++u) {
      float v0 = axy[r][u], v1 = axx[r][u], v2 = ayy[r][u];
      #pragma unroll
      for (int d = 1; d <= 8; d <<= 1) {
        v0 += __shfl_xor(v0, d);
        v1 += __shfl_xor(v1, d);
        v2 += __shfl_xor(v2, d);
      }
      if (slice == 0) {
        const int idx = (4 * ti + r) * 16 + (4 * tk + u);
        if (A.atomicMode) {
          atomicAdd(&fin[idx],       (double)v0);
          atomicAdd(&fin[256 + idx], (double)v1);
          atomicAdd(&fin[512 + idx], (double)v2);
        } else {
          rec[(size_t)idx * cnt]         = v0;
          rec[(size_t)(256 + idx) * cnt] = v1;
          rec[(size_t)(512 + idx) * cnt] = v2;
        }
      }
    }
  }
  // ---- Z reduction: butterfly over the 32 column-group lanes ----
  #pragma unroll
  for (int d = 1; d <= 16; d <<= 1) {
    #pragma unroll
    for (int q = 0; q < 4; ++q) z[q] += __shfl_xor(z[q], d);
  }
  if (g == 0) {
    #pragma unroll
    for (int q = 0; q < 4; ++q) zstage[mat * 16 + 4 * hw + q] = z[q];
  }
  __syncthreads();
  if (t < 32) {
    const float s = zstage[t];
    if (A.atomicMode) atomicAdd(&fin[768 + t], (double)s);
    else              rec[(size_t)(768 + t) * cnt] = s;
  }
}

// One block per (pair, value): coalesced contiguous read, fp64 reduce, store.
__global__ __launch_bounds__(256) void reduce_kernel(const float* __restrict__ partial,
                                                     double* __restrict__ finalG,
                                                     int nb0, int nb1, int nb2) {
  const int b = blockIdx.x;
  const int p = b / 800;
  const int v = b - 800 * p;
  const int cnt   = (p == 0) ? nb0 : (p == 1) ? nb1 : nb2;
  const int start = (p == 0) ? 0   : (p == 1) ? nb0 : nb0 + nb1;
  const float* src = partial + (size_t)800 * start + (size_t)v * cnt;
  double s = 0.0;
  for (int r = threadIdx.x; r < cnt; r += 256) s += (double)src[r];
  #pragma unroll
  for (int d = 1; d <= 32; d <<= 1) s += __shfl_xor(s, d);
  __shared__ double ls[4];
  if ((threadIdx.x & 63) == 0) ls[threadIdx.x >> 6] = s;
  __syncthreads();
  if (threadIdx.x == 0) finalG[p * 800 + v] = (ls[0] + ls[1]) + (ls[2] + ls[3]);
}

__device__ __forceinline__ float expm1_poly(float d) {
  float p = 1.0f / 120.0f;
  p = fmaf(p, d, 1.0f / 24.0f);
  p = fmaf(p, d, 1.0f / 6.0f);
  p = fmaf(p, d, 0.5f);
  return fmaf(d * d, p, d);
}
__device__ __forceinline__ float log1p_poly(float w) {
  float p = -1.0f / 6.0f;
  p = fmaf(p, w, 1.0f / 5.0f);
  p = fmaf(p, w, -1.0f / 4.0f);
  p = fmaf(p, w, 1.0f / 3.0f);
  p = fmaf(p, w, -0.5f);
  return fmaf(w * w, p, w);
}

// blocks: 2p -> (f,g) chains of pair p ; 2p+1 -> (a,b) self chains
__global__ __launch_bounds__(64) void sinkhorn_kernel(const double* __restrict__ finalG,
                                                      double* __restrict__ result,
                                                      EpsList E) {
  const int p    = blockIdx.x >> 1;
  const int half = blockIdx.x & 1;
  const int lane = threadIdx.x;
  const int pot  = lane >> 5;
  const int i    = (lane >> 1) & 15;
  const int jh   = lane & 1;
  const double* G = finalG + p * 800;

  float Crow[8];
  #pragma unroll
  for (int jj = 0; jj < 8; ++jj) {
    const int j = jh * 8 + jj;
    double Cv;
    if (half == 0) {
      const int r = (pot == 0) ? i : j;
      const int c = (pot == 0) ? j : i;
      const double zr = G[768 + r], zc = G[784 + c];
      const double sr = G[256 + 17 * r] / (zr * zr);
      const double sc = G[512 + 17 * c] / (zc * zc);
      Cv = 0.5 * (sr + sc) - G[16 * r + c] / (zr * zc);
    } else if (pot == 0) {
      const double zi_ = G[768 + i], zj_ = G[768 + j];
      const double si_ = G[256 + 17 * i] / (zi_ * zi_);
      const double sj_ = G[256 + 17 * j] / (zj_ * zj_);
      Cv = 0.5 * (si_ + sj_) - G[256 + 16 * i + j] / (zi_ * zj_);
    } else {
      const double zi_ = G[784 + i], zj_ = G[784 + j];
      const double si_ = G[512 + 17 * i] / (zi_ * zi_);
      const double sj_ = G[512 + 17 * j] / (zj_ * zj_);
      Cv = 0.5 * (si_ + sj_) - G[512 + 16 * i + j] / (zi_ * zj_);
    }
    Crow[jj] = (float)Cv;
  }

  const int srcBase = (half == 0) ? ((pot == 0) ? 32 : 0)
                                  : ((pot == 0) ? 0 : 32);
  float h = 0.0f;

  #pragma unroll 1
  for (int n = 0; n < NSTEP; ++n) {
    const float eps  = E.e[n];
    const float inve = 1.0f / eps;
    float q = 0.0f;
    #pragma unroll
    for (int jj = 0; jj < 8; ++jj) {
      const float hj = __shfl(h, srcBase + 2 * (jh * 8 + jj));
      q += expm1_poly((hj - Crow[jj]) * inve);
    }
    q += __shfl_xor(q, 1);
    const float val = -eps * log1p_poly(q * (1.0f / 16.0f));
    h = 0.5f * (h + val);
  }
  {
    const float eps  = 0.0025f;
    const float inve = 1.0f / eps;
    float q = 0.0f;
    #pragma unroll
    for (int jj = 0; jj < 8; ++jj) {
      const float hj = __shfl(h, srcBase + 2 * (jh * 8 + jj));
      q += expm1_poly((hj - Crow[jj]) * inve);
    }
    q += __shfl_xor(q, 1);
    h = -eps * log1p_poly(q * (1.0f / 16.0f));
  }
  float s = h;
  #pragma unroll
  for (int d = 1; d <= 32; d <<= 1) s += __shfl_xor(s, d);
  if (lane == 0) result[blockIdx.x] = (double)(s * (1.0f / 32.0f));
}

__global__ void finalize_kernel(const double* __restrict__ result, float* __restrict__ out) {
  const double s = (result[0] - result[1]) + (result[2] - result[3]) + (result[4] - result[5]);
  out[0] = (float)(s / 3.0);
}

extern "C" void kernel_launch(void* const* d_in, const int* in_sizes, int n_in,
                              void* d_out, int out_size, void* d_ws, size_t ws_size,
                              hipStream_t stream) {
  int idx[6] = {0, 1, 2, 3, 4, 5};
  for (int a = 1; a < 6; ++a) {
    const int key = idx[a];
    int b = a - 1;
    while (b >= 0 && in_sizes[idx[b]] < in_sizes[key]) { idx[b + 1] = idx[b]; --b; }
    idx[b + 1] = key;
  }

  const float* xs[3]; const float* ys[3]; int Ms[3]; int nb[3];
  for (int p = 0; p < 3; ++p) {
    xs[p] = (const float*)d_in[idx[2 * p]];
    ys[p] = (const float*)d_in[idx[2 * p + 1]];
    Ms[p] = in_sizes[idx[2 * p]] / 16;
    nb[p] = Ms[p] / COLS_PER_BLOCK;
  }
  const int totalBlocks = nb[0] + nb[1] + nb[2];

  const size_t partialBytes = (size_t)totalBlocks * 800 * sizeof(float);
  const size_t finalBytes   = (size_t)(2400 + 8) * sizeof(double);
  const bool partialMode    = (ws_size >= partialBytes + finalBytes);

  char* wsb      = (char*)d_ws;
  float* partial = partialMode ? (float*)wsb : nullptr;
  double* finalG = (double*)(wsb + (partialMode ? partialBytes : 0));
  double* result = finalG + 2400;

  hipMemsetAsync(finalG, 0, finalBytes, stream);

  GramArgs A;
  A.x0 = xs[0]; A.y0 = ys[0];
  A.x1 = xs[1]; A.y1 = ys[1];
  A.x2 = xs[2]; A.y2 = ys[2];
  A.M0 = Ms[0]; A.M1 = Ms[1]; A.M2 = Ms[2];
  A.bs1 = nb[0]; A.bs2 = nb[0] + nb[1]; A.bsTot = totalBlocks;
  A.partial = partial; A.finalG = finalG;
  A.atomicMode = partialMode ? 0 : 1;

  gram_kernel<<<dim3(totalBlocks), dim3(TPB), 0, stream>>>(A);
  if (partialMode)
    reduce_kernel<<<dim3(2400), dim3(256), 0, stream>>>(partial, finalG, nb[0], nb[1], nb[2]);

  EpsList E;
  const double base = 0.95 * 0.95;
  for (int n = 0; n < NSTEP; ++n) {
    double v = pow(base, (double)n);
    if (v < 0.0025) v = 0.0025;
    E.e[n] = (float)v;
  }
  sinkhorn_kernel<<<dim3(6), dim3(64), 0, stream>>>(finalG, result, E);
  finalize_kernel<<<dim3(1), dim3(1), 0, stream>>>(result, (float*)d_out);
}